// Round 1
// baseline (1167.228 us; speedup 1.0000x reference)
//
#include <hip/hip_runtime.h>
#include <stdint.h>

// ConvTranspose2d-shaped op per jax.lax.conv_transpose(transpose_kernel=True,
// dimension_numbers=("NCHW","IOHW","NCHW"), VALID, stride 1):
//   out[co,oh,ow] = sum_{ci,kh,kw} x[ci,oh-kh,ow-kw] * w[co, ci, kh, kw]
// Contraction is over AXIS 1 of w[64,64,3,3]; output channel is AXIS 0.
// Implicit-GEMM bf16 MFMA 16x16x32; A/B/D layouts validated r1-r3:
//   A: m=lane&15, k=quad*8+j ; B: n=lane&15, k=quad*8+j ; D: row=4*quad+reg, col=lane&15.
//
// R4: latency-bound per rocprof (MfmaUtil 4.6%, HBM 12%, occupancy 21%) —
// stage->barrier->compute->barrier was fully serialized. This version:
//   * double-buffered LDS (2 x 26KB)
//   * T14 async-stage split: issue next tile's global loads into regs BEFORE
//     the MFMA phase; wait+convert+ds_write AFTER; one barrier per iteration.
//   * boundary handling via clamped-address unconditional loads + select at
//     pack time, so all 56 loads/thread issue early and unconditionally.

typedef short s16x8 __attribute__((ext_vector_type(8)));
typedef float f32x4 __attribute__((ext_vector_type(4)));

#define HIN   1024
#define WIN   1024
#define OHT   1026
#define OWT   1026
#define TH    4     // output rows per tile
#define TW    32    // output cols per tile
#define LRN   6     // TH+2 staged input rows
#define LCN   34    // TW+2 staged input cols
#define ROWG  64    // grid.y
#define NTILE 257   // ceil(1026/4)
#define CELLS (8 * LRN * LCN)   // 1632 staging cells (each = 8 ci x 1 pixel)
#define NPRE  7                 // ceil(1632/256) cells per thread

__device__ __forceinline__ short f2bf(float v) {
    return __builtin_bit_cast(short, (__bf16)v);
}

__global__ __launch_bounds__(256, 2)
void convt_mfma(const float* __restrict__ x, const float* __restrict__ w,
                float* __restrict__ out) {
    // LDS x tile: [buf][lr][lc][ci] bf16, ci innermost; 16B chunk c stored at
    // (c ^ (lc&7)) so MFMA B-fragment reads are bank-conflict-free.
    __shared__ __align__(16) short lds[2][LRN * LCN * 64];

    const int tid  = threadIdx.x;
    const int wave = tid >> 6;
    const int lane = tid & 63;
    const int n    = lane & 15;   // MFMA col (pixel) / A-row (co) lane index
    const int quad = lane >> 4;   // 0..3

    const int ow0 = blockIdx.x * TW;

    // ---- Preload A fragments (weights), whole K=576 for this wave's 16 co ----
    // kk: tap=kk>>1 (kh*3+kw), ci=(kk&1)*32 + quad*8 + j ; w[co,ci,tap]=w[co*576+ci*9+tap]
    const int co_a = (wave << 4) + n;
    s16x8 afrag[18];
    #pragma unroll
    for (int kk = 0; kk < 18; ++kk) {
        const int tap = kk >> 1;
        const int cib = ((kk & 1) << 5) + (quad << 3);
        const float* wp = w + co_a * 576 + tap;
        #pragma unroll
        for (int j = 0; j < 8; ++j)
            afrag[kk][j] = f2bf(wp[(cib + j) * 9]);
    }

    // Prefetch registers: one tile's staging data (56 fp32/thread).
    float pre[NPRE][8];

    // Issue-early: unconditional loads from clamped addresses (x is 256MB, so
    // base=0 is always safe); validity re-derived at commit time.
    auto prefetch = [&](int rt) {
        const int oh0 = rt * TH;
        #pragma unroll
        for (int i = 0; i < NPRE; ++i) {
            const int cell = tid + (i << 8);
            const int c    = cell / (LRN * LCN);
            const int rem  = cell - c * (LRN * LCN);
            const int lr   = rem / LCN;
            const int lc   = rem - lr * LCN;
            const int ih   = oh0 - 2 + lr;
            const int iw   = ow0 - 2 + lc;
            const bool ok  = (cell < CELLS) && ((unsigned)ih < (unsigned)HIN)
                           && ((unsigned)iw < (unsigned)WIN);
            const long base = ok ? ((long)(c << 3) * (HIN * WIN) + (long)ih * WIN + iw) : 0;
            #pragma unroll
            for (int j = 0; j < 8; ++j)
                pre[i][j] = x[base + (long)j * (HIN * WIN)];
        }
    };

    // Write-late: convert + pack + swizzled ds_write (waits on the loads here).
    auto commit = [&](int rt, int buf) {
        #pragma unroll
        for (int i = 0; i < NPRE; ++i) {
            const int cell = tid + (i << 8);
            if (cell < CELLS) {   // i<6 folds to true; i==6 divergent on tid<96
                const int c    = cell / (LRN * LCN);
                const int rem  = cell - c * (LRN * LCN);
                const int lr   = rem / LCN;
                const int lc   = rem - lr * LCN;
                const int ih   = rt * TH - 2 + lr;
                const int iw   = ow0 - 2 + lc;
                const bool ok  = ((unsigned)ih < (unsigned)HIN)
                               && ((unsigned)iw < (unsigned)WIN);
                s16x8 pv;
                #pragma unroll
                for (int j = 0; j < 8; ++j)
                    pv[j] = ok ? f2bf(pre[i][j]) : (short)0;
                const int ch = c ^ (lc & 7);
                *(s16x8*)&lds[buf][(lr * LCN + lc) * 64 + ch * 8] = pv;
            }
        }
    };

    int rt  = blockIdx.y;
    int cur = 0;
    prefetch(rt);
    commit(rt, 0);
    __syncthreads();

    while (true) {
        const int rtn   = rt + ROWG;
        const bool more = (rtn < NTILE);

        // Issue next tile's loads before the compute phase (latency hides
        // under 144 ds_read+MFMA).
        if (more) prefetch(rtn);

        // ---- MFMA main loop (reads lds[cur]) ----
        f32x4 acc[TH][2];
        #pragma unroll
        for (int r = 0; r < TH; ++r)
            #pragma unroll
            for (int nt = 0; nt < 2; ++nt)
                acc[r][nt] = (f32x4){0.f, 0.f, 0.f, 0.f};

        const short* lp = &lds[cur][0];
        #pragma unroll
        for (int kk = 0; kk < 18; ++kk) {
            const int tap = kk >> 1;
            const int kh  = tap / 3;
            const int kw  = tap - kh * 3;
            const int cq  = ((kk & 1) << 2) + quad;
            #pragma unroll
            for (int r = 0; r < TH; ++r) {
                const int lr = r + 2 - kh;
                #pragma unroll
                for (int nt = 0; nt < 2; ++nt) {
                    const int lc = nt * 16 + n + 2 - kw;
                    const int ch = cq ^ (lc & 7);
                    const s16x8 b = *(const s16x8*)&lp[(lr * LCN + lc) * 64 + ch * 8];
                    acc[r][nt] = __builtin_amdgcn_mfma_f32_16x16x32_bf16(
                        afrag[kk], b, acc[r][nt], 0, 0, 0);
                }
            }
        }

        // ---- Store: D row(co)=4*quad+reg, col(pixel)=lane&15 ----
        const int oh0 = rt * TH;
        #pragma unroll
        for (int r = 0; r < TH; ++r) {
            const int oh = oh0 + r;
            if (oh < OHT) {
                #pragma unroll
                for (int nt = 0; nt < 2; ++nt) {
                    const int ow = ow0 + nt * 16 + n;
                    if (ow < OWT) {
                        const int co = (wave << 4) + (quad << 2);
                        float* op = out + (long)co * (OHT * OWT) + (long)oh * OWT + ow;
                        #pragma unroll
                        for (int reg = 0; reg < 4; ++reg)
                            op[(long)reg * (OHT * OWT)] = acc[r][nt][reg];
                    }
                }
            }
        }

        if (!more) break;
        // Wait for prefetch loads (compute phase covered their latency),
        // convert+write into the other buffer; single barrier per iteration.
        commit(rtn, cur ^ 1);
        __syncthreads();
        cur ^= 1;
        rt  = rtn;
    }
}

extern "C" void kernel_launch(void* const* d_in, const int* in_sizes, int n_in,
                              void* d_out, int out_size, void* d_ws, size_t ws_size,
                              hipStream_t stream) {
    const int i_x = (in_sizes[0] > in_sizes[1]) ? 0 : 1;
    const float* x = (const float*)d_in[i_x];     // [64,1024,1024]
    const float* w = (const float*)d_in[1 - i_x]; // [64,64,3,3]
    float* out = (float*)d_out;                   // [64,1026,1026]

    dim3 grid((OWT + TW - 1) / TW, ROWG);         // 33 x 64
    dim3 block(256);
    convt_mfma<<<grid, block, 0, stream>>>(x, w, out);
}

// Round 2
// 695.241 us; speedup vs baseline: 1.6789x; 1.6789x over previous
//
#include <hip/hip_runtime.h>
#include <stdint.h>

// ConvTranspose2d per jax.lax.conv_transpose(transpose_kernel=True,
// ("NCHW","IOHW","NCHW"), VALID, stride 1):
//   out[co,oh,ow] = sum_{ci,kh,kw} x[ci,oh-kh,ow-kw] * w[co, ci, kh, kw]
// Implicit-GEMM bf16 MFMA 16x16x32; layouts validated r1-r3:
//   A: m=lane&15, k=quad*8+j ; B: n=lane&15, k=quad*8+j ; D: row=4*quad+reg, col=lane&15.
//
// R2 (post R1 spill post-mortem): latency/MLP-bound, NOT BW-bound (R1 hit
// 1.8 TB/s with scratch garbage). Fixes, none holding fp32 across MFMA:
//  * staging: dwordx4 supercell loads (4 lc x 8 ci), ALL loads of both
//    supercells issued before the first wait (counted vmcnt), convert+write
//    after. Transient 64 f32 regs live only in the staging phase.
//  * MFMA loop restructured over (khalf,lr,nt,o): B-fragment reused across
//    kh -> 72 ds_read_b128 (was 144) feeding 144 MFMAs in short independent
//    chains (different acc regs) the scheduler can pipeline.
//  * double-buffered LDS, ONE barrier per iteration.
//  * nontemporal output stores (write-once; keep x halo in L2).

typedef short s16x8 __attribute__((ext_vector_type(8)));
typedef float f32x4 __attribute__((ext_vector_type(4)));
typedef float f32x4u __attribute__((ext_vector_type(4), aligned(4)));

#define HIN   1024
#define WIN   1024
#define OHT   1026
#define OWT   1026
#define TH    4     // output rows per tile
#define TW    32    // output cols per tile
#define LRN   6     // TH+2 staged input rows
#define LCN   34    // TW+2 staged input cols (used)
#define LCP   36    // padded LDS row stride (vector staging writes lc 0..35)
#define ROWG  64    // grid.y
#define NTILE 257   // ceil(1026/4)
#define NSC   432   // supercells: 8 c-chunks * 6 lr * 9 lc4

__device__ __forceinline__ short f2bf(float v) {
    return __builtin_bit_cast(short, (__bf16)v);
}

struct SC { f32x4 v[8]; };   // one supercell: 8 ci x 4 consecutive iw

__global__ __launch_bounds__(256, 2)
void convt_mfma(const float* __restrict__ x, const float* __restrict__ w,
                float* __restrict__ out) {
    // LDS x tile: [buf][lr][lc][ci] bf16, ci innermost; 16B chunk c stored at
    // (c ^ (lc&7)) so MFMA B-fragment reads are bank-conflict-free.
    __shared__ __align__(16) short lds[2][LRN * LCP * 64];

    const int tid  = threadIdx.x;
    const int wave = tid >> 6;
    const int lane = tid & 63;
    const int n    = lane & 15;   // MFMA col (pixel) / A-row (co) lane index
    const int quad = lane >> 4;   // 0..3

    const int ow0 = blockIdx.x * TW;

    // ---- Preload A fragments (weights), whole K=576 for this wave's 16 co ----
    // kk: tap=kk>>1 (kh*3+kw), ci=(kk&1)*32+quad*8+j ; w[co,ci,tap]=w[co*576+ci*9+tap]
    const int co_a = (wave << 4) + n;
    s16x8 afrag[18];
    #pragma unroll
    for (int kk = 0; kk < 18; ++kk) {
        const int tap = kk >> 1;
        const int cib = ((kk & 1) << 5) + (quad << 3);
        const float* wp = w + co_a * 576 + tap;
        #pragma unroll
        for (int j = 0; j < 8; ++j)
            afrag[kk][j] = f2bf(wp[(cib + j) * 9]);
    }

    // ---- Staging helpers (supercell = 4 lc x 8 ci of one chunk) ----
    auto loadSC = [&](int s, int rt) -> SC {
        SC r;
        const int c   = s / 54;          // 54 = LRN*9
        const int rem = s - c * 54;
        const int lr  = rem / 9;
        const int lc4 = rem - lr * 9;
        const int ih  = rt * TH - 2 + lr;
        const int iw0 = ow0 - 2 + (lc4 << 2);
        const bool ihok = (unsigned)ih < (unsigned)HIN;
        if (ihok && iw0 >= 0 && iw0 <= WIN - 4) {
            const long base = (long)(c << 3) * (HIN * WIN) + (long)ih * WIN + iw0;
            #pragma unroll
            for (int j = 0; j < 8; ++j)
                r.v[j] = *(const f32x4u*)&x[base + (long)j * (HIN * WIN)];
        } else {
            #pragma unroll
            for (int j = 0; j < 8; ++j) {
                #pragma unroll
                for (int l = 0; l < 4; ++l) {
                    const int iw = iw0 + l;
                    const bool ok = ihok && ((unsigned)iw < (unsigned)WIN);
                    r.v[j][l] = ok
                        ? x[(long)((c << 3) + j) * (HIN * WIN) + (long)ih * WIN + iw]
                        : 0.0f;
                }
            }
        }
        return r;
    };
    auto writeSC = [&](int s, int buf, const SC& d) {
        const int c   = s / 54;
        const int rem = s - c * 54;
        const int lr  = rem / 9;
        const int lc4 = rem - lr * 9;
        #pragma unroll
        for (int l = 0; l < 4; ++l) {
            const int lc = (lc4 << 2) + l;
            s16x8 pv;
            #pragma unroll
            for (int j = 0; j < 8; ++j)
                pv[j] = f2bf(d.v[j][l]);
            const int ch = c ^ (lc & 7);
            *(s16x8*)&lds[buf][(lr * LCP + lc) * 64 + ch * 8] = pv;
        }
    };
    // Stage one tile: issue ALL loads (both supercells) before first use so
    // 16 dwordx4 stay in flight per thread; then convert + swizzled ds_write.
    auto stage = [&](int rt, int buf) {
        const int s1 = tid, s2 = tid + 256;
        SC a = loadSC(s1, rt);
        SC b;
        if (s2 < NSC) b = loadSC(s2, rt);
        writeSC(s1, buf, a);
        if (s2 < NSC) writeSC(s2, buf, b);
    };

    int rt  = blockIdx.y;
    int cur = 0;
    stage(rt, 0);
    __syncthreads();

    while (true) {
        const int rtn = rt + ROWG;
        // Stage next tile into the other buffer (overlaps other waves' MFMA).
        if (rtn < NTILE) stage(rtn, cur ^ 1);

        // ---- MFMA: 72 B-reads feeding 144 MFMAs (B reused across kh) ----
        f32x4 acc[TH][2];
        #pragma unroll
        for (int r = 0; r < TH; ++r)
            #pragma unroll
            for (int nt = 0; nt < 2; ++nt)
                acc[r][nt] = (f32x4){0.f, 0.f, 0.f, 0.f};

        const short* lp = &lds[cur][0];
        #pragma unroll
        for (int khalf = 0; khalf < 2; ++khalf) {
            const int cq = (khalf << 2) + quad;
            #pragma unroll
            for (int lr = 0; lr < LRN; ++lr) {
                #pragma unroll
                for (int nt = 0; nt < 2; ++nt) {
                    #pragma unroll
                    for (int o = 0; o < 3; ++o) {     // o = 2-kw
                        const int lc = nt * 16 + n + o;
                        const int ch = cq ^ (lc & 7);
                        const s16x8 b = *(const s16x8*)&lp[(lr * LCP + lc) * 64 + ch * 8];
                        const int kw = 2 - o;
                        #pragma unroll
                        for (int kh = 0; kh < 3; ++kh) {
                            const int r = lr - 2 + kh;
                            if (r >= 0 && r < TH) {
                                const int kk = (kh * 3 + kw) * 2 + khalf;
                                acc[r][nt] = __builtin_amdgcn_mfma_f32_16x16x32_bf16(
                                    afrag[kk], b, acc[r][nt], 0, 0, 0);
                            }
                        }
                    }
                }
            }
        }

        // ---- Store: D row(co)=4*quad+reg, col(pixel)=lane&15 ----
        const int oh0 = rt * TH;
        #pragma unroll
        for (int r = 0; r < TH; ++r) {
            const int oh = oh0 + r;
            if (oh < OHT) {
                #pragma unroll
                for (int nt = 0; nt < 2; ++nt) {
                    const int ow = ow0 + nt * 16 + n;
                    if (ow < OWT) {
                        const int co = (wave << 4) + (quad << 2);
                        float* op = out + (long)co * (OHT * OWT) + (long)oh * OWT + ow;
                        #pragma unroll
                        for (int reg = 0; reg < 4; ++reg)
                            __builtin_nontemporal_store(acc[r][nt][reg],
                                                        op + (long)reg * (OHT * OWT));
                    }
                }
            }
        }

        if (rtn >= NTILE) break;
        __syncthreads();   // buf^1 fully written; safe to flip
        cur ^= 1;
        rt = rtn;
    }
}

extern "C" void kernel_launch(void* const* d_in, const int* in_sizes, int n_in,
                              void* d_out, int out_size, void* d_ws, size_t ws_size,
                              hipStream_t stream) {
    const int i_x = (in_sizes[0] > in_sizes[1]) ? 0 : 1;
    const float* x = (const float*)d_in[i_x];     // [64,1024,1024]
    const float* w = (const float*)d_in[1 - i_x]; // [64,64,3,3]
    float* out = (float*)d_out;                   // [64,1026,1026]

    dim3 grid((OWT + TW - 1) / TW, ROWG);         // 33 x 64
    dim3 block(256);
    convt_mfma<<<grid, block, 0, stream>>>(x, w, out);
}

// Round 3
// 639.511 us; speedup vs baseline: 1.8252x; 1.0871x over previous
//
#include <hip/hip_runtime.h>
#include <stdint.h>

// ConvTranspose2d per jax.lax.conv_transpose(transpose_kernel=True,
// ("NCHW","IOHW","NCHW"), VALID, stride 1):
//   out[co,oh,ow] = sum_{ci,kh,kw} x[ci,oh-kh,ow-kw] * w[co, ci, kh, kw]
// Implicit-GEMM bf16 MFMA 16x16x32; layouts validated r1-r3:
//   A: m=lane&15, k=quad*8+j ; B: n=lane&15, k=quad*8+j ; D: row=4*quad+reg, col=lane&15.
//
// R3 (post R2 post-mortem):
//  * drop nontemporal stores (caused 1.6x write amp + RMW phantom fetch).
//  * swizzle ch = c ^ ((lc ^ (lc>>3)) & 7): conflict-free for BOTH the
//    lc-stride-4 ds_writes (R2 regression: 6M conflicts) and the
//    lc-consecutive ds_reads.
//  * true T14: 512-thread blocks, ONE supercell (32 VGPR) held per thread;
//    8 waves = 4 co-groups x 2 pixel-halves (36 ds_read + 72 MFMA each).
//    Loop: issue loads(t+1) -> sched_barrier -> MFMA(t) -> store ->
//    commit(t+1) [vmcnt lands HERE, after compute] -> one barrier.

typedef short s16x8 __attribute__((ext_vector_type(8)));
typedef float f32x4 __attribute__((ext_vector_type(4)));
typedef float f32x4u __attribute__((ext_vector_type(4), aligned(4)));

#define HIN   1024
#define WIN   1024
#define OHT   1026
#define OWT   1026
#define TH    4     // output rows per tile
#define TW    32    // output cols per tile
#define LRN   6     // TH+2 staged input rows
#define LCP   36    // padded LDS row stride (staging writes lc 0..35)
#define ROWG  64    // grid.y
#define NTILE 257   // ceil(1026/4)
#define NSC   432   // supercells: 8 c-chunks * 6 lr * 9 lc4
#define PLANE (HIN * WIN)

__device__ __forceinline__ short f2bf(float v) {
    return __builtin_bit_cast(short, (__bf16)v);
}
__device__ __forceinline__ int swz(int c, int lc) {
    return c ^ ((lc ^ (lc >> 3)) & 7);
}

__global__ __launch_bounds__(512, 2)
void convt_mfma(const float* __restrict__ x, const float* __restrict__ w,
                float* __restrict__ out) {
    // LDS x tile: [buf][lr][lc][ci] bf16, ci innermost; 16B chunk c at slot
    // swz(c,lc) -> bank-conflict-free for stride-4 writes AND stride-1 reads.
    __shared__ __align__(16) short lds[2][LRN * LCP * 64];

    const int tid  = threadIdx.x;
    const int wave = tid >> 6;
    const int lane = tid & 63;
    const int n    = lane & 15;   // MFMA col (pixel) / A-row (co) lane index
    const int quad = lane >> 4;   // 0..3
    const int g    = wave & 3;    // co group (co = g*16 + ...)
    const int h    = wave >> 2;   // pixel half (cols h*16 .. h*16+15)

    const int ow0 = blockIdx.x * TW;

    // ---- Preload A fragments (weights), whole K=576 for this group's 16 co ----
    // kk = 2*tap + khalf; ci = khalf*32 + quad*8 + j ; w[co,ci,tap]=w[co*576+ci*9+tap]
    const int co_a = (g << 4) + n;
    s16x8 afrag[18];
    #pragma unroll
    for (int kk = 0; kk < 18; ++kk) {
        const int tap = kk >> 1;
        const int cib = ((kk & 1) << 5) + (quad << 3);
        const float* wp = w + co_a * 576 + tap;
        #pragma unroll
        for (int j = 0; j < 8; ++j)
            afrag[kk][j] = f2bf(wp[(cib + j) * 9]);
    }

    // ---- Per-thread staging constants (supercell = 8 ci x 4 consecutive iw) ----
    const bool active = tid < NSC;
    const int  c    = tid / 54;          // 54 = LRN*9
    const int  rem  = tid - c * 54;
    const int  lr   = rem / 9;
    const int  lc4  = rem - lr * 9;
    const int  iw0  = ow0 - 2 + (lc4 << 2);
    const bool iwfast = (iw0 >= 0) && (iw0 <= WIN - 4);
    const long cbase  = (long)(c << 3) * PLANE;

    f32x4 pre[8];   // held across the MFMA phase (32 VGPR)

    auto prefetch = [&](int rt) {
        const int  ih   = rt * TH - 2 + lr;
        const bool ihok = (unsigned)ih < (unsigned)HIN;
        if (active && ihok && iwfast) {
            const long base = cbase + (long)ih * WIN + iw0;
            #pragma unroll
            for (int j = 0; j < 8; ++j)
                pre[j] = *(const f32x4u*)&x[base + (long)j * PLANE];
        } else if (active && ihok) {
            #pragma unroll
            for (int j = 0; j < 8; ++j)
                #pragma unroll
                for (int l = 0; l < 4; ++l) {
                    const int iw = iw0 + l;
                    pre[j][l] = ((unsigned)iw < (unsigned)WIN)
                        ? x[cbase + (long)j * PLANE + (long)ih * WIN + iw]
                        : 0.0f;
                }
        } else {
            #pragma unroll
            for (int j = 0; j < 8; ++j)
                pre[j] = (f32x4){0.f, 0.f, 0.f, 0.f};
        }
    };

    auto commit = [&](int buf) {
        if (active) {
            #pragma unroll
            for (int l = 0; l < 4; ++l) {
                const int lc = (lc4 << 2) + l;
                s16x8 pv;
                #pragma unroll
                for (int j = 0; j < 8; ++j)
                    pv[j] = f2bf(pre[j][l]);
                *(s16x8*)&lds[buf][(lr * LCP + lc) * 64 + swz(c, lc) * 8] = pv;
            }
        }
    };

    int rt  = blockIdx.y;
    int cur = 0;
    prefetch(rt);
    commit(0);
    __syncthreads();

    while (true) {
        const int  rtn  = rt + ROWG;
        const bool more = (rtn < NTILE);

        if (more) prefetch(rtn);            // issue loads only
        __builtin_amdgcn_sched_barrier(0);  // pin: loads issued before MFMA

        // ---- MFMA: 36 B-reads feeding 72 MFMAs (B reused across kh) ----
        f32x4 acc[TH];
        #pragma unroll
        for (int r = 0; r < TH; ++r)
            acc[r] = (f32x4){0.f, 0.f, 0.f, 0.f};

        const short* lp = &lds[cur][0];
        #pragma unroll
        for (int khalf = 0; khalf < 2; ++khalf) {
            const int cq = (khalf << 2) + quad;
            #pragma unroll
            for (int plr = 0; plr < LRN; ++plr) {
                #pragma unroll
                for (int o = 0; o < 3; ++o) {     // o = 2-kw
                    const int lc = (h << 4) + n + o;
                    const s16x8 b =
                        *(const s16x8*)&lp[(plr * LCP + lc) * 64 + swz(cq, lc) * 8];
                    const int kw = 2 - o;
                    #pragma unroll
                    for (int kh = 0; kh < 3; ++kh) {
                        const int r = plr - 2 + kh;
                        if (r >= 0 && r < TH) {
                            acc[r] = __builtin_amdgcn_mfma_f32_16x16x32_bf16(
                                afrag[(kh * 3 + kw) * 2 + khalf], b, acc[r], 0, 0, 0);
                        }
                    }
                }
            }
        }

        // ---- Store: D row(co)=4*quad+reg, col(pixel)=lane&15 ----
        const int oh0 = rt * TH;
        const int ow  = ow0 + (h << 4) + n;
        if (ow < OWT) {
            #pragma unroll
            for (int r = 0; r < TH; ++r) {
                const int oh = oh0 + r;
                if (oh < OHT) {
                    const int co = (g << 4) + (quad << 2);
                    float* op = out + (long)co * (OHT * OWT) + (long)oh * OWT + ow;
                    #pragma unroll
                    for (int reg = 0; reg < 4; ++reg)
                        op[(long)reg * (OHT * OWT)] = acc[r][reg];
                }
            }
        }

        if (!more) break;
        commit(cur ^ 1);     // vmcnt wait lands here, AFTER the MFMA phase
        __syncthreads();
        cur ^= 1;
        rt = rtn;
    }
}

extern "C" void kernel_launch(void* const* d_in, const int* in_sizes, int n_in,
                              void* d_out, int out_size, void* d_ws, size_t ws_size,
                              hipStream_t stream) {
    const int i_x = (in_sizes[0] > in_sizes[1]) ? 0 : 1;
    const float* x = (const float*)d_in[i_x];     // [64,1024,1024]
    const float* w = (const float*)d_in[1 - i_x]; // [64,64,3,3]
    float* out = (float*)d_out;                   // [64,1026,1026]

    dim3 grid((OWT + TW - 1) / TW, ROWG);         // 33 x 64
    dim3 block(512);
    convt_mfma<<<grid, block, 0, stream>>>(x, w, out);
}